// Round 2
// baseline (102.411 us; speedup 1.0000x reference)
//
#include <hip/hip_runtime.h>
#include <math.h>

// ChamferLikeDistanceLoss on MI355X (gfx950)
// B=4, 1x64x64 fp32 images. out = mean_i min_j |g_i - b_j| + mean_j min_i |.|
// g = sobel-magnitude(depth_pred), b = boundary_gt, per batch.
//
// R2 design: values are scalars -> 1-D nearest-value brute scan, VALU-bound.
//  K1: sobel for all B*4096 pixels -> d_ws (flat global), also zeroes d_out.
//  K2: each thread = 1 query, scans its batch's 4096 refs via UNIFORM global
//      loads (scalarizable to s_load through K$ -- no per-CU LDS pipe
//      serialization like R1's ds_read_b128 broadcast scan), min-combining
//      with fminf(fminf(m,|a|),|b|) -> v_min3_f32 + abs modifiers.
// Model: K2 wave = 4096 sub + 2048 min3 = 6144 VALU * 2cy = 12.3K cy ~ 5.1us.

#define N_PIX 4096   // 64*64
#define BLK   256
#define CHUNKS_PER_IMG 16   // 4096 / 256 queries per block

__device__ __forceinline__ float sobel_g(const float* __restrict__ d, int pix) {
    const int y = pix >> 6;
    const int x = pix & 63;
    const float a00 = (y > 0 && x > 0)  ? d[(y - 1) * 64 + (x - 1)] : 0.f;
    const float a01 = (y > 0)           ? d[(y - 1) * 64 + x]       : 0.f;
    const float a02 = (y > 0 && x < 63) ? d[(y - 1) * 64 + (x + 1)] : 0.f;
    const float a10 = (x > 0)           ? d[y * 64 + (x - 1)]       : 0.f;
    const float a12 = (x < 63)          ? d[y * 64 + (x + 1)]       : 0.f;
    const float a20 = (y < 63 && x > 0) ? d[(y + 1) * 64 + (x - 1)] : 0.f;
    const float a21 = (y < 63)          ? d[(y + 1) * 64 + x]       : 0.f;
    const float a22 = (y < 63 && x < 63)? d[(y + 1) * 64 + (x + 1)] : 0.f;
    const float gx = (a00 - a02) + 2.f * (a10 - a12) + (a20 - a22);
    const float gy = (a00 + 2.f * a01 + a02) - (a20 + 2.f * a21 + a22);
    return sqrtf(gx * gx + gy * gy + 1e-8f);
}

// K1: g_ws[b*4096 + p] = sobel(depth[b], p). Also zero-init the output
// accumulator (d_out is poisoned 0xAA before every launch).
__global__ __launch_bounds__(BLK) void sobel_all_kernel(
    const float* __restrict__ depth, float* __restrict__ g_ws,
    float* __restrict__ out)
{
    const int gid = blockIdx.x * BLK + threadIdx.x;   // 0 .. B*4096-1
    const int batch = gid >> 12;
    const int pix   = gid & (N_PIX - 1);
    g_ws[gid] = sobel_g(depth + batch * N_PIX, pix);
    if (gid == 0) out[0] = 0.f;
}

// K2: both chamfer directions. blockIdx: [0, B*16) = dir0, [B*16, 2*B*16) = dir1.
__global__ __launch_bounds__(BLK) void chamfer_kernel(
    const float* __restrict__ g_ws, const float* __restrict__ bnd,
    float* __restrict__ out, int blocks_per_dir, float inv_count)
{
    __shared__ float bsum;

    const int tid = threadIdx.x;
    const int bx  = blockIdx.x;
    const int dir = (bx >= blocks_per_dir) ? 1 : 0;
    const int rem = dir ? (bx - blocks_per_dir) : bx;
    const int batch = rem >> 4;           // CHUNKS_PER_IMG == 16
    const int chunk = rem & (CHUNKS_PER_IMG - 1);

    const float* __restrict__ gb = g_ws + batch * N_PIX;
    const float* __restrict__ bb = bnd  + batch * N_PIX;

    if (tid == 0) bsum = 0.f;
    __syncthreads();

    const int pix = chunk * BLK + tid;
    // dir0: queries = g, refs = b.  dir1: queries = b, refs = g.
    const float q = dir ? bb[pix] : gb[pix];
    const float4* __restrict__ ref4 = (const float4*)(dir ? gb : bb);

    // Uniform (wave-invariant) address scan -> SMEM/K$ path; min3 combine.
    float m0 = 1e30f, m1 = 1e30f;
    #pragma unroll 8
    for (int j = 0; j < N_PIX / 4; ++j) {
        const float4 r = ref4[j];
        m0 = fminf(fminf(m0, fabsf(q - r.x)), fabsf(q - r.y));  // v_min3 x2
        m1 = fminf(fminf(m1, fabsf(q - r.z)), fabsf(q - r.w));
    }
    float m = fminf(m0, m1);

    // Wave(64) shuffle reduce -> block LDS atomic -> one global atomic.
    #pragma unroll
    for (int o = 32; o > 0; o >>= 1) m += __shfl_down(m, o);
    if ((tid & 63) == 0) atomicAdd(&bsum, m);
    __syncthreads();
    if (tid == 0) atomicAdd(out, bsum * inv_count);
}

extern "C" void kernel_launch(void* const* d_in, const int* in_sizes, int n_in,
                              void* d_out, int out_size, void* d_ws, size_t ws_size,
                              hipStream_t stream) {
    const float* depth = (const float*)d_in[0];
    const float* bnd   = (const float*)d_in[1];
    float* out  = (float*)d_out;
    float* g_ws = (float*)d_ws;   // B*4096 floats = 64 KiB of the workspace

    const int B = in_sizes[0] / N_PIX;              // 4
    const int blocks_per_dir = B * CHUNKS_PER_IMG;  // 64
    const float inv_count = 1.0f / (float)(B * N_PIX);

    hipLaunchKernelGGL(sobel_all_kernel, dim3(B * N_PIX / BLK), dim3(BLK), 0,
                       stream, depth, g_ws, out);
    hipLaunchKernelGGL(chamfer_kernel, dim3(2 * blocks_per_dir), dim3(BLK), 0,
                       stream, g_ws, bnd, out, blocks_per_dir, inv_count);
}

// Round 3
// 76.844 us; speedup vs baseline: 1.3327x; 1.3327x over previous
//
#include <hip/hip_runtime.h>
#include <math.h>

// ChamferLikeDistanceLoss on MI355X (gfx950)
// B=4, 1x64x64 fp32. out = mean_i min_j |g_i - b_j| + mean_j min_i |g_i - b_j|
// g = sobel-magnitude(depth_pred), b = boundary_gt, per batch.
//
// R3: refs-in-registers + rotating-query ring.
//  - R1 (LDS broadcast scan): LDS pipe-bound, ~12 cy/ds_read_b128 x 1024 x
//    waves/CU -> ~29 us. R2 (uniform global scan): latency-bound, 48.6 us.
//  - R3: each 64-lane wave holds ALL 4096 refs in VGPRs (64/lane). The 64
//    queries (1/lane) rotate around the wave with their running min m.
//    LDS traffic: 2 bpermutes/step (vs 1024 b128 reads) -> pure VALU-bound.
//  - Model: 64 steps x ~99 VALU x 2cy ~ 12.8K cy ~ 5.3 us @ 1 wave/SIMD.
//
// K1: sobel for all B*4096 pixels -> d_ws; zero-inits d_out.
// K2: 512 blocks x 64 threads = 2 dirs x 4 batches x 64 query-waves.

#define N_PIX 4096   // 64*64

__device__ __forceinline__ float sobel_g(const float* __restrict__ d, int pix) {
    const int y = pix >> 6;
    const int x = pix & 63;
    const float a00 = (y > 0 && x > 0)  ? d[(y - 1) * 64 + (x - 1)] : 0.f;
    const float a01 = (y > 0)           ? d[(y - 1) * 64 + x]       : 0.f;
    const float a02 = (y > 0 && x < 63) ? d[(y - 1) * 64 + (x + 1)] : 0.f;
    const float a10 = (x > 0)           ? d[y * 64 + (x - 1)]       : 0.f;
    const float a12 = (x < 63)          ? d[y * 64 + (x + 1)]       : 0.f;
    const float a20 = (y < 63 && x > 0) ? d[(y + 1) * 64 + (x - 1)] : 0.f;
    const float a21 = (y < 63)          ? d[(y + 1) * 64 + x]       : 0.f;
    const float a22 = (y < 63 && x < 63)? d[(y + 1) * 64 + (x + 1)] : 0.f;
    const float gx = (a00 - a02) + 2.f * (a10 - a12) + (a20 - a22);
    const float gy = (a00 + 2.f * a01 + a02) - (a20 + 2.f * a21 + a22);
    return sqrtf(gx * gx + gy * gy + 1e-8f);
}

// K1: g_ws[b*4096+p] = sobel(depth[b],p); also zero-init out (poisoned 0xAA).
__global__ __launch_bounds__(256) void sobel_all_kernel(
    const float* __restrict__ depth, float* __restrict__ g_ws,
    float* __restrict__ out)
{
    const int gid = blockIdx.x * 256 + threadIdx.x;   // 0 .. B*4096-1
    const int batch = gid >> 12;
    const int pix   = gid & (N_PIX - 1);
    g_ws[gid] = sobel_g(depth + batch * N_PIX, pix);
    if (gid == 0) out[0] = 0.f;
}

// K2: one wave per block. blockIdx: dir = bx>>8, batch = (bx>>6)&3, qblk = bx&63.
__global__ __launch_bounds__(64) void chamfer_ring_kernel(
    const float* __restrict__ g_ws, const float* __restrict__ bnd,
    float* __restrict__ out, float inv_count)
{
    const int lane  = threadIdx.x;
    const int bx    = blockIdx.x;
    const int dir   = bx >> 8;        // 256 blocks per direction
    const int batch = (bx >> 6) & 3;  // 64 blocks per batch
    const int qblk  = bx & 63;        // 64 queries per block

    const float* __restrict__ gb = g_ws + batch * N_PIX;
    const float* __restrict__ bb = bnd  + batch * N_PIX;
    const float* __restrict__ qsrc = dir ? bb : gb;
    const float* __restrict__ rsrc = dir ? gb : bb;

    // This lane's query.
    float q = qsrc[qblk * 64 + lane];

    // Stage all 4096 refs into registers: 64/lane, coalesced dwordx4.
    // Partition: r[4j+c] = rsrc[j*256 + 4*lane + c]  (any partition is valid:
    // every query visits every lane).
    float r[64];
    const float4* __restrict__ r4 = (const float4*)rsrc;
    #pragma unroll
    for (int j = 0; j < 16; ++j) {
        const float4 v = r4[j * 64 + lane];
        r[4 * j + 0] = v.x; r[4 * j + 1] = v.y;
        r[4 * j + 2] = v.z; r[4 * j + 3] = v.w;
    }

    // Ring: (q, m) rotate together; each step scans this lane's 64 refs with
    // two independent min3 chains (latency-chain break).
    float m = 1e30f;
    const int src = (lane + 1) & 63;
    for (int step = 0; step < 64; ++step) {
        const float q_next = __shfl(q, src);   // issued early, hides latency
        float t0 = 1e30f, t1 = 1e30f;
        #pragma unroll
        for (int k = 0; k < 64; k += 4) {
            t0 = fminf(fminf(t0, fabsf(q - r[k + 0])), fabsf(q - r[k + 1]));
            t1 = fminf(fminf(t1, fabsf(q - r[k + 2])), fabsf(q - r[k + 3]));
        }
        m = fminf(m, fminf(t0, t1));
        m = __shfl(m, src);                    // off critical path of next step
        q = q_next;
    }
    // After 64 rotations (q,m) are home; m = min_j |q - ref_j|.

    // Wave sum -> one atomic per block.
    #pragma unroll
    for (int o = 32; o > 0; o >>= 1) m += __shfl_down(m, o);
    if (lane == 0) atomicAdd(out, m * inv_count);
}

extern "C" void kernel_launch(void* const* d_in, const int* in_sizes, int n_in,
                              void* d_out, int out_size, void* d_ws, size_t ws_size,
                              hipStream_t stream) {
    const float* depth = (const float*)d_in[0];
    const float* bnd   = (const float*)d_in[1];
    float* out  = (float*)d_out;
    float* g_ws = (float*)d_ws;   // B*4096 floats = 64 KiB of workspace

    const int B = in_sizes[0] / N_PIX;              // 4
    const float inv_count = 1.0f / (float)(B * N_PIX);

    hipLaunchKernelGGL(sobel_all_kernel, dim3(B * N_PIX / 256), dim3(256), 0,
                       stream, depth, g_ws, out);
    hipLaunchKernelGGL(chamfer_ring_kernel, dim3(2 * B * 64), dim3(64), 0,
                       stream, g_ws, bnd, out, inv_count);
}